// Round 1
// baseline (17.702 us; speedup 1.0000x reference)
//
#include <hip/hip_runtime.h>
#include <hip/hip_bf16.h>

#define H  128
#define W  128
#define HO 127
#define WO 127

__global__ __launch_bounds__(128) void quonv_kernel(
    const float* __restrict__ img,   // [B,128,128,1]
    const float* __restrict__ wts,   // [2,4]
    float* __restrict__ out)         // [B,127,127,4]
{
    // ---- per-block: sincos of weight half-angles into LDS (8 lanes only) ----
    __shared__ float wc[8], ws_[8];
    const int t = threadIdx.x;
    if (t < 8) {
        float a = 0.5f * wts[t];
        float s, c;
        __sincosf(a, &s, &c);
        wc[t] = c;
        ws_[t] = s;
    }
    __syncthreads();

    const int j = t;             // output col
    const int i = blockIdx.y;    // output row
    const int b = blockIdx.z;    // batch
    if (j >= WO) return;

    // ---- load the 2x2 patch (wire order: (0,0),(0,1),(1,0),(1,1)) ----
    const float* row0 = img + ((size_t)b * H + i) * W;
    const float* row1 = row0 + W;
    float p[4];
    p[0] = row0[j];
    p[1] = row0[j + 1];
    p[2] = row1[j];
    p[3] = row1[j + 1];

    // ---- embedding: product state from per-wire (cos,sin) of pi*p/2 ----
    float ec[4], es[4];
#pragma unroll
    for (int w = 0; w < 4; ++w) {
        __sincosf(1.57079632679489662f * p[w], &es[w], &ec[w]);
    }

    float t01[4], t23[4];
#pragma unroll
    for (int b0 = 0; b0 < 2; ++b0)
#pragma unroll
        for (int b1 = 0; b1 < 2; ++b1) {
            t01[b0 * 2 + b1] = (b0 ? es[0] : ec[0]) * (b1 ? es[1] : ec[1]);
            t23[b0 * 2 + b1] = (b0 ? es[2] : ec[2]) * (b1 ? es[3] : ec[3]);
        }

    // state index: bit of wire w is bit (3-w) of idx
    float st[16];
#pragma unroll
    for (int idx = 0; idx < 16; ++idx)
        st[idx] = t01[idx >> 2] * t23[idx & 3];

    // ---- 2 entangling layers: 4x RY(weights) then CNOT ring ----
#pragma unroll
    for (int l = 0; l < 2; ++l) {
#pragma unroll
        for (int w = 0; w < 4; ++w) {
            const float cc = wc[l * 4 + w];
            const float ss = ws_[l * 4 + w];
            const int m = 8 >> w;
#pragma unroll
            for (int idx = 0; idx < 16; ++idx) {
                if (!(idx & m)) {
                    const float a = st[idx];
                    const float bb = st[idx | m];
                    st[idx]     = cc * a - ss * bb;
                    st[idx | m] = ss * a + cc * bb;
                }
            }
        }
        // CNOT ring (0,1),(1,2),(2,3),(3,0): swap target pair where ctrl==1
#pragma unroll
        for (int q = 0; q < 4; ++q) {
            const int mc = 8 >> q;
            const int mt = 8 >> ((q + 1) & 3);
#pragma unroll
            for (int idx = 0; idx < 16; ++idx) {
                if ((idx & mc) && !(idx & mt)) {
                    const float tmp = st[idx];
                    st[idx]      = st[idx | mt];
                    st[idx | mt] = tmp;
                }
            }
        }
    }

    // ---- expectation <Z_w> = sum (+/-) st^2 ----
    float e0 = 0.f, e1 = 0.f, e2 = 0.f, e3 = 0.f;
#pragma unroll
    for (int idx = 0; idx < 16; ++idx) {
        const float pr = st[idx] * st[idx];
        e0 += (idx & 8) ? -pr : pr;
        e1 += (idx & 4) ? -pr : pr;
        e2 += (idx & 2) ? -pr : pr;
        e3 += (idx & 1) ? -pr : pr;
    }

    float4 o = make_float4(e0, e1, e2, e3);
    *reinterpret_cast<float4*>(out + (((size_t)b * HO + i) * WO + j) * 4) = o;
}

extern "C" void kernel_launch(void* const* d_in, const int* in_sizes, int n_in,
                              void* d_out, int out_size, void* d_ws, size_t ws_size,
                              hipStream_t stream) {
    const float* img = (const float*)d_in[0];
    const float* wts = (const float*)d_in[1];
    float* out = (float*)d_out;

    const int B = in_sizes[0] / (H * W);   // 64
    dim3 grid(1, HO, B);
    dim3 block(128, 1, 1);
    quonv_kernel<<<grid, block, 0, stream>>>(img, wts, out);
}